// Round 9
// baseline (565.345 us; speedup 1.0000x reference)
//
#include <hip/hip_runtime.h>
#include <math.h>

// Problem constants: D=2048, E=8, T=32768, top_k=2
constexpr int D_DIM = 2048;
constexpr int NEXP  = 8;
constexpr int NTOK  = 32768;
constexpr int TT    = 2;             // tokens per wave
constexpr int SR    = 256;           // k-rows per super (1 KiB of one token-row)
constexpr int NS    = D_DIM / SR;    // 8 supers
constexpr int WPB   = 4;             // waves per block (256 threads)

typedef float vf4 __attribute__((ext_vector_type(4)));
typedef float vf2 __attribute__((ext_vector_type(2)));

__device__ __forceinline__ float softplus_f(float x) {
    return (x > 20.0f) ? x : log1pf(expf(x));
}

// v8: ZERO barriers, ZERO LDS. Theory: every prior LDS variant drained all
// in-flight loads once per super (__syncthreads => s_waitcnt vmcnt(0)),
// nullifying prefetch depth -> all plateaued at ~101-110 us kernel. Here:
//  - h: explicit 3-super lookahead via named hbuf[4] rotation (static idx),
//    issued at iteration top; sched_barrier(0) pins issue order so the
//    compiler cannot sink loads to uses (the r2 failure: VGPR=52, 202 us).
//  - W: read per r-slice straight from global (lane L reads its own 32
//    contiguous floats at lane*32); all 16 waves/CU read the same 16 KiB
//    per super -> L1/L2-hot after the first toucher. Rolling slice prefetch.
//  - lane map / butterfly / epilogue identical to v7 (harness-verified).
__global__ __launch_bounds__(256, 4)
void noisy_topk_router(const float* __restrict__ h,
                       const float* __restrict__ Ww,
                       const float* __restrict__ bw,
                       const float* __restrict__ Wn,
                       const float* __restrict__ bn,
                       const float* __restrict__ eps,
                       float* __restrict__ out_sparse,
                       float* __restrict__ out_ix,
                       float* __restrict__ out_full)
{
    const int tid  = threadIdx.x;
    const int lane = tid & 63;
    const int wave = tid >> 6;
    const int t0   = (blockIdx.x * WPB + wave) * TT;
    const int role = lane & 1;

    const float* hbase = h  + (size_t)t0 * D_DIM + 4 * lane;
    const float* ww    = Ww + lane * 32;          // rows 4L..4L+3, experts 0..7
    const float* wn    = Wn + lane * 32;

    // p2[t*8 + m*4 + eh] = partials for outputs (m, 2eh)/(m, 2eh+1), token t0+t
    vf2 p2[TT * 8];
#pragma unroll
    for (int i = 0; i < TT * 8; ++i) p2[i] = vf2{0.0f, 0.0f};

    // ---- h pipeline: 3-super lookahead, named rotation (all static idx) ----
    vf4 hbuf[4][TT];
#pragma unroll
    for (int k = 0; k < 3; ++k)
#pragma unroll
        for (int t = 0; t < TT; ++t)
            hbuf[k][t] = *(const vf4*)(hbase + (size_t)t * D_DIM + k * SR);

#pragma unroll
    for (int S = 0; S < NS; ++S) {
        // issue super S+3's h loads NOW; consumed 3 iterations later
        if (S + 3 < NS) {
#pragma unroll
            for (int t = 0; t < TT; ++t)
                hbuf[(S + 3) & 3][t] =
                    *(const vf4*)(hbase + (size_t)t * D_DIM + (S + 3) * SR);
        }
        __builtin_amdgcn_sched_barrier(0);   // pin: prefetch must not sink below

        const int soff = S * 2048;           // floats per matrix per super

        // rolling W slices: slice r = row r (of this lane's 4), experts 0..7
        vf4 ca0 = *(const vf4*)(ww + soff + 0);
        vf4 ca1 = *(const vf4*)(ww + soff + 4);
        vf4 cb0 = *(const vf4*)(wn + soff + 0);
        vf4 cb1 = *(const vf4*)(wn + soff + 4);
#pragma unroll
        for (int r = 0; r < 4; ++r) {
            vf4 na0, na1, nb0, nb1;
            if (r < 3) {
                na0 = *(const vf4*)(ww + soff + (r + 1) * 8);
                na1 = *(const vf4*)(ww + soff + (r + 1) * 8 + 4);
                nb0 = *(const vf4*)(wn + soff + (r + 1) * 8);
                nb1 = *(const vf4*)(wn + soff + (r + 1) * 8 + 4);
            }
            const vf2 a0lo = {ca0[0], ca0[1]}, a0hi = {ca0[2], ca0[3]};
            const vf2 a1lo = {ca1[0], ca1[1]}, a1hi = {ca1[2], ca1[3]};
            const vf2 b0lo = {cb0[0], cb0[1]}, b0hi = {cb0[2], cb0[3]};
            const vf2 b1lo = {cb1[0], cb1[1]}, b1hi = {cb1[2], cb1[3]};
#pragma unroll
            for (int t = 0; t < TT; ++t) {
                const float x = hbuf[S & 3][t][r];
                const vf2 xx = {x, x};
                p2[t*8 + 0] = __builtin_elementwise_fma(xx, a0lo, p2[t*8 + 0]);
                p2[t*8 + 1] = __builtin_elementwise_fma(xx, a0hi, p2[t*8 + 1]);
                p2[t*8 + 2] = __builtin_elementwise_fma(xx, a1lo, p2[t*8 + 2]);
                p2[t*8 + 3] = __builtin_elementwise_fma(xx, a1hi, p2[t*8 + 3]);
                p2[t*8 + 4] = __builtin_elementwise_fma(xx, b0lo, p2[t*8 + 4]);
                p2[t*8 + 5] = __builtin_elementwise_fma(xx, b0hi, p2[t*8 + 5]);
                p2[t*8 + 6] = __builtin_elementwise_fma(xx, b1lo, p2[t*8 + 6]);
                p2[t*8 + 7] = __builtin_elementwise_fma(xx, b1hi, p2[t*8 + 7]);
            }
            if (r < 3) { ca0 = na0; ca1 = na1; cb0 = nb0; cb1 = nb1; }
        }
    }

    // ---- 5-step compacting butterfly over 32 values + cross-half add ----
    // value j: t=j>>4, o8=(j>>1)&7, m=j&1. After 5 LSB-first steps lane L
    // holds q[0] = value (L&31) summed over its 32-lane half; xor-32 add
    // completes the 64-lane sum. Lanes 32-63 mirror lanes 0-31. (verified v7)
    float q[32];
#pragma unroll
    for (int j = 0; j < 32; ++j) {
        const int t = j >> 4, m = j & 1, e = (j >> 2) & 3, el = (j >> 1) & 1;
        q[j] = p2[t*8 + m*4 + e][el];
    }
#pragma unroll
    for (int s = 0; s < 5; ++s) {
        const int mm = 1 << s;
        const bool hi = (lane & mm) != 0;
        const int n = 32 >> (s + 1);
#pragma unroll
        for (int j = 0; j < n; ++j) {
            float a  = q[2 * j];
            float b  = q[2 * j + 1];
            float ta = __shfl_xor(a, mm, 64);
            float tb = __shfl_xor(b, mm, 64);
            q[j] = hi ? (b + tb) : (a + ta);
        }
    }
    const float r0 = q[0] + __shfl_xor(q[0], 32, 64);

    // Epilogue (verified): lane L<32 -> token t0+(L>>4), expert (L>>1)&7,
    // matrix L&1. (lane>>4)&1 clamps mirror lanes to valid tokens.
    const int  o         = (lane >> 1) & 7;
    const bool noiseLane = (role != 0);
    const int  tok       = t0 + ((lane >> 4) & 1);
    const float bias     = noiseLane ? bn[o] : bw[o];

    const float val = r0 + bias;                // logit (role 0) or noise-logit (role 1)
    const float sp  = softplus_f(val);
    const float spN = __shfl_xor(sp, 1, 64);    // logit lane <- partner's softplus
    const float ev  = eps[(size_t)tok * NEXP + o];
    const float noisy = val + ev * spN;         // meaningful on logit lanes

    // argmax over the 8 logit lanes (same token, role 0): masks {2,4,8}
    float v0 = noisy; int i0 = o;
#pragma unroll
    for (int m = 2; m <= 8; m <<= 1) {
        float ov = __shfl_xor(v0, m, 64);
        int   oi = __shfl_xor(i0, m, 64);
        bool take = (ov > v0) || (ov == v0 && oi < i0);
        v0 = take ? ov : v0;
        i0 = take ? oi : i0;
    }
    // second argmax (exclude i0)
    float v1 = (o == i0) ? -INFINITY : noisy; int i1 = o;
#pragma unroll
    for (int m = 2; m <= 8; m <<= 1) {
        float ov = __shfl_xor(v1, m, 64);
        int   oi = __shfl_xor(i1, m, 64);
        bool take = (ov > v1) || (ov == v1 && oi < i1);
        v1 = take ? ov : v1;
        i1 = take ? oi : i1;
    }
    // full softmax over 8 experts
    const float ex = expf(noisy - v0);
    float ssum = ex;
#pragma unroll
    for (int m = 2; m <= 8; m <<= 1) ssum += __shfl_xor(ssum, m, 64);
    const float fullv = ex / ssum;
    // sparse softmax over the top-2 (others exactly 0)
    const float dd  = expf(v1 - v0);
    const float den = 1.0f + dd;
    const float sparsev = (o == i0) ? (1.0f / den)
                        : (o == i1) ? (dd / den) : 0.0f;

    if (!noiseLane && lane < 32) {
        out_sparse[(size_t)tok * NEXP + o] = sparsev;
        out_full  [(size_t)tok * NEXP + o] = fullv;
        if (o == 0) {
            out_ix[(size_t)tok * 2]     = (float)i0;
            out_ix[(size_t)tok * 2 + 1] = (float)i1;
        }
    }
}

extern "C" void kernel_launch(void* const* d_in, const int* in_sizes, int n_in,
                              void* d_out, int out_size, void* d_ws, size_t ws_size,
                              hipStream_t stream) {
    const float* h   = (const float*)d_in[0];
    const float* Ww  = (const float*)d_in[1];
    const float* bw  = (const float*)d_in[2];
    const float* Wn  = (const float*)d_in[3];
    const float* bn  = (const float*)d_in[4];
    const float* eps = (const float*)d_in[5];
    // d_in[6] = top_k (always 2 for this problem)

    float* out_sparse = (float*)d_out;                         // [T, 8]
    float* out_ix     = out_sparse + (size_t)NTOK * NEXP;      // [T, 2] (as float)
    float* out_full   = out_ix + (size_t)NTOK * 2;             // [T, 8]

    const int grid = NTOK / (TT * WPB);  // 4096 blocks x 256 threads
    noisy_topk_router<<<grid, 256, 0, stream>>>(h, Ww, bw, Wn, bn, eps,
                                                out_sparse, out_ix, out_full);
}